// Round 5
// baseline (253.077 us; speedup 1.0000x reference)
//
#include <hip/hip_runtime.h>
#include <math.h>

// PANLoss: dice(regions) + 0.5*dice(kernels) + 0.25*(agg + dis)
//
// R13 = block-role specialization (stream-count / DRAM-page-locality probe).
//
// History: R9 LDS-atomics (regressed, DS pipe), R10 G=5 tail amortization
// (82->51us, real win), R11 occupancy cap + 32-bit addressing (neutral),
// R12 cross-stream phase rotation (neutral). pan_main pinned ~51us =
// 5.1 TB/s delivered vs 6.9 TB/s the harness's own single-stream fills
// sustain; no pipe counter saturated. Last distinguishing feature vs the
// fill: 10 interleaved streams PER WAVE, 25MiB apart -> DRAM row thrash.
//
// R13 splits roles: grid.x = [0,80) tree blocks (sim x4 + labels = 6
// streams, 24B/px), [80,160) dice blocks (pr/gr then pk/gk = 2 active
// streams at a time, 16B/px). Byte-balanced 60/40 across uniform
// dispatch; per-role reduction tails shrink (45 vs 6 quantities).
//
// Pre-committed: neutral result => mixed-stream read ceiling reached
// => ROOFLINE next round.
//
// ws per batch (NACC=51 floats, slots 0,9,18,27,36 unused/zero):
//   [1..8] ct  [10..17] ck  [19..26] St  [28..35] Sk  [37..44] Ss
//   [45..47] regions pg/pp/gg   [48..50] kernels pg/pp/gg

#define NSEG 9
#define NACC 51
#define NBATCH 16
#define EPSF 1e-5f
#define G 5          // float4 groups per thread
#define BPB 80       // blocks per role per batch: 102400 float4 / (256*G)

typedef float  vfloat4 __attribute__((ext_vector_type(4)));
typedef int    vint4   __attribute__((ext_vector_type(4)));

__device__ __forceinline__ float wave_reduce_sum(float v) {
#pragma unroll
    for (int off = 32; off > 0; off >>= 1)
        v += __shfl_down(v, off, 64);
    return v;
}

__device__ __forceinline__ float sigm(float x) {
    return 1.0f / (1.0f + __expf(-x));
}

__device__ __forceinline__ vfloat4 nt_load4(const float* p) {
    return __builtin_nontemporal_load((const vfloat4*)p);
}
__device__ __forceinline__ vint4 nt_load4i(const int* p) {
    return __builtin_nontemporal_load((const vint4*)p);
}

__global__ __launch_bounds__(256, 5) void pan_main(
    const float* __restrict__ pred_r, const float* __restrict__ gt_r,
    const float* __restrict__ pred_k, const float* __restrict__ gt_k,
    const float* __restrict__ sim,
    const int* __restrict__ tlab, const int* __restrict__ klab,
    float* __restrict__ ws, int npix)
{
    const int tid = threadIdx.x;
    const int b = blockIdx.y;
    const int base = b * npix;
    const int lane = tid & 63;
    const int wv = tid >> 6;

    __shared__ float red[4][NACC];

    if (blockIdx.x < BPB) {
        // ================= TREE role: sim x4 + tlab + klab =================
        const int sbase = b * 4 * npix;
        int bx = blockIdx.x + 5 * b;
        if (bx >= BPB) bx -= BPB;
        const int i0 = bx * (256 * G) + tid;

        float St_[8], Sk_[8], Ss_[8];
        unsigned ct_[8], ck_[8];
#pragma unroll
        for (int s = 0; s < 8; ++s) {
            St_[s] = 0.0f; Sk_[s] = 0.0f; Ss_[s] = 0.0f;
            ct_[s] = 0u; ck_[s] = 0u;
        }

#pragma unroll 1
        for (int g = 0; g < G; ++g) {
            const int e = (i0 + g * 256) * 4;
            const vfloat4 c0 = nt_load4(sim + sbase + e);
            const vfloat4 c1 = nt_load4(sim + sbase + npix + e);
            const vfloat4 c2 = nt_load4(sim + sbase + 2 * npix + e);
            const vfloat4 c3 = nt_load4(sim + sbase + 3 * npix + e);
            const vint4 tl = nt_load4i(tlab + base + e);
            const vint4 kl = nt_load4i(klab + base + e);

            const float s2x = c0.x*c0.x + c1.x*c1.x + c2.x*c2.x + c3.x*c3.x;
            const float s2y = c0.y*c0.y + c1.y*c1.y + c2.y*c2.y + c3.y*c3.y;
            const float s2z = c0.z*c0.z + c1.z*c1.z + c2.z*c2.z + c3.z*c3.z;
            const float s2w = c0.w*c0.w + c1.w*c1.w + c2.w*c2.w + c3.w*c3.w;

#define DO_COMP(TL, KL, S2)                                      \
            {                                                    \
                bool tt = ((TL) == s);                           \
                bool kk = ((KL) == s);                           \
                ct_[s - 1] += (unsigned)__popcll(__ballot(tt));  \
                ck_[s - 1] += (unsigned)__popcll(__ballot(kk));  \
                St_[s - 1] += tt ? (S2) : 0.0f;                  \
                Sk_[s - 1] += kk ? (S2) : 0.0f;                  \
                Ss_[s - 1] += (tt && kk) ? (S2) : 0.0f;          \
            }
#pragma unroll
            for (int s = 1; s <= 8; ++s) {
                DO_COMP(tl.x, kl.x, s2x);
                DO_COMP(tl.y, kl.y, s2y);
                DO_COMP(tl.z, kl.z, s2z);
                DO_COMP(tl.w, kl.w, s2w);
            }
#undef DO_COMP
        }

#pragma unroll
        for (int s = 0; s < 8; ++s) {
            float v;
            v = wave_reduce_sum(St_[s]); if (lane == 0) red[wv][19 + s] = v;
            v = wave_reduce_sum(Sk_[s]); if (lane == 0) red[wv][28 + s] = v;
            v = wave_reduce_sum(Ss_[s]); if (lane == 0) red[wv][37 + s] = v;
        }
        if (lane == 0) {
#pragma unroll
            for (int s = 0; s < 8; ++s) {
                red[wv][1 + s] = (float)ct_[s];
                red[wv][10 + s] = (float)ck_[s];
            }
            red[wv][0] = 0.0f; red[wv][9] = 0.0f; red[wv][18] = 0.0f;
            red[wv][27] = 0.0f; red[wv][36] = 0.0f;
        }
        __syncthreads();
        if (tid < 45) {
            float s = red[0][tid] + red[1][tid] + red[2][tid] + red[3][tid];
            atomicAdd(&ws[b * NACC + tid], s);
        }
    } else {
        // ================= DICE role: pr/gr then pk/gk =================
        int bx = (blockIdx.x - BPB) + 5 * b + 40;
        bx %= BPB;
        const int i0 = bx * (256 * G) + tid;

        float rpg = 0.0f, rpp = 0.0f, rgg = 0.0f;
        float kpg = 0.0f, kpp = 0.0f, kgg = 0.0f;

#pragma unroll 1
        for (int g = 0; g < G; ++g) {
            const int e = (i0 + g * 256) * 4;
            const vfloat4 pr = nt_load4(pred_r + base + e);
            const vfloat4 gr = nt_load4(gt_r + base + e);
            {
                float p;
                p = sigm(pr.x); rpg += p * gr.x; rpp += p * p; rgg += gr.x;
                p = sigm(pr.y); rpg += p * gr.y; rpp += p * p; rgg += gr.y;
                p = sigm(pr.z); rpg += p * gr.z; rpp += p * p; rgg += gr.z;
                p = sigm(pr.w); rpg += p * gr.w; rpp += p * p; rgg += gr.w;
            }
            const vfloat4 pk = nt_load4(pred_k + base + e);
            const vfloat4 gk = nt_load4(gt_k + base + e);
            {
                float p;
                p = sigm(pk.x); kpg += p * gk.x; kpp += p * p; kgg += gk.x;
                p = sigm(pk.y); kpg += p * gk.y; kpp += p * p; kgg += gk.y;
                p = sigm(pk.z); kpg += p * gk.z; kpp += p * p; kgg += gk.z;
                p = sigm(pk.w); kpg += p * gk.w; kpp += p * p; kgg += gk.w;
            }
        }

        {
            float v;
            v = wave_reduce_sum(rpg); if (lane == 0) red[wv][45] = v;
            v = wave_reduce_sum(rpp); if (lane == 0) red[wv][46] = v;
            v = wave_reduce_sum(rgg); if (lane == 0) red[wv][47] = v;
            v = wave_reduce_sum(kpg); if (lane == 0) red[wv][48] = v;
            v = wave_reduce_sum(kpp); if (lane == 0) red[wv][49] = v;
            v = wave_reduce_sum(kgg); if (lane == 0) red[wv][50] = v;
        }
        __syncthreads();
        if (tid < 6) {
            int q = 45 + tid;
            float s = red[0][q] + red[1][q] + red[2][q] + red[3][q];
            atomicAdd(&ws[b * NACC + q], s);
        }
    }
}

__global__ __launch_bounds__(64) void pan_finalize(
    const float* __restrict__ ws, float* __restrict__ out)
{
    const int b = threadIdx.x;
    float dice_r = 0.0f, dice_k = 0.0f, lagg = 0.0f, ldis = 0.0f;

    if (b < NBATCH) {
        const float* w = ws + b * NACC;
        {
            float pg = w[45], pp = w[46], gg = w[47];
            dice_r = 1.0f - (2.0f * pg + EPSF) / ((pp + EPSF) + (gg + EPSF));
            pg = w[48]; pp = w[49]; gg = w[50];
            dice_k = 1.0f - (2.0f * pg + EPSF) / ((pp + EPSF) + (gg + EPSF));
        }
        float a[8];
#pragma unroll
        for (int i = 1; i < NSEG; ++i) {
            float ct = w[i], ck = w[NSEG + i];
            float St = w[2 * NSEG + i], Sk = w[3 * NSEG + i], Ss = w[4 * NSEG + i];
            float inv = 1.0f / (ck + 1.0f);
            float omi = 1.0f - inv;
            float n2 = omi * omi * Ss + (St - Ss) + inv * inv * (Sk - Ss);
            float nrm = sqrtf(n2);
            float d = nrm - 0.5f;  // SIGMA_AGG (no clamp — matches reference)
            lagg += logf(d * d + 1.0f) / (ct + 1.0f);
            float ckd = ck + 0.001f;
            a[i - 1] = Sk / (ckd * ckd);
        }
#pragma unroll
        for (int i = 0; i < 8; ++i) {
#pragma unroll
            for (int j = i + 1; j < 8; ++j) {
                float pair = 3.0f - sqrtf(a[i] + a[j]);  // SIGMA_DIS
                ldis += logf(pair * pair + 1.0f);
            }
        }
        ldis *= (1.0f / 56.0f);  // K_MAX*(K_MAX-1)
    }

    dice_r = wave_reduce_sum(dice_r);
    dice_k = wave_reduce_sum(dice_k);
    lagg = wave_reduce_sum(lagg);
    ldis = wave_reduce_sum(ldis);

    if (threadIdx.x == 0) {
        float loss = dice_r + 0.5f * dice_k + 0.25f * (lagg + ldis);
        out[0] = loss;
        out[1] = dice_r;
        out[2] = dice_k;
        out[3] = lagg;
        out[4] = ldis;
    }
}

extern "C" void kernel_launch(void* const* d_in, const int* in_sizes, int n_in,
                              void* d_out, int out_size, void* d_ws, size_t ws_size,
                              hipStream_t stream) {
    const float* pred_r = (const float*)d_in[0];
    const float* gt_r   = (const float*)d_in[1];
    const float* pred_k = (const float*)d_in[2];
    const float* gt_k   = (const float*)d_in[3];
    const float* sim    = (const float*)d_in[4];
    const int*   tlab   = (const int*)d_in[5];
    const int*   klab   = (const int*)d_in[6];
    float* out = (float*)d_out;
    float* ws  = (float*)d_ws;

    const int npix = in_sizes[0] / NBATCH;  // 640*640 = 409600

    (void)hipMemsetAsync(ws, 0, NBATCH * NACC * sizeof(float), stream);

    dim3 grid(2 * BPB, NBATCH);  // [0,80) tree blocks, [80,160) dice blocks
    pan_main<<<grid, 256, 0, stream>>>(pred_r, gt_r, pred_k, gt_k, sim,
                                       tlab, klab, ws, npix);
    pan_finalize<<<1, 64, 0, stream>>>(ws, out);
}